// Round 6
// baseline (376.640 us; speedup 1.0000x reference)
//
#include <hip/hip_runtime.h>
#include <hip/hip_bf16.h>
#include <math.h>

// B=4, T=2048, D=1024, E=8, F=1024, top_k=2
#define NTOK 8192   // B*T
#define D_DIM 1024
#define E_DIM 8
#define F_DIM 1024

// cnt is padded: counter for expert e lives at cnt[e*32] (128 B apart) so the
// 8 experts' global atomics land in different L2 lines.
#define CNT_STRIDE 32

typedef __attribute__((ext_vector_type(8))) short bf16x8;
typedef __attribute__((ext_vector_type(4))) float f32x4;

typedef const __attribute__((address_space(1))) unsigned int* as1_uint_ptr;
typedef __attribute__((address_space(3))) unsigned int* as3_uint_ptr;

__device__ __forceinline__ void async_load16(const void* g, void* l) {
    // per-lane global address; LDS dest = wave-uniform base + lane*16
    __builtin_amdgcn_global_load_lds((as1_uint_ptr)g, (as3_uint_ptr)l, 16, 0, 0);
}

__device__ __forceinline__ float bf2f(unsigned short b) {
    unsigned int u = ((unsigned int)b) << 16;
    return __builtin_bit_cast(float, u);
}
__device__ __forceinline__ unsigned short f2bf(float f) {
    __hip_bfloat16 h = __float2bfloat16(f);
    return __builtin_bit_cast(unsigned short, h);
}

// LDS swizzle: stage lane s loads k-chunk (s&3)^((row>>1)&3); readers invert.
// SQ_LDS_BANK_CONFLICT measured 0.
//
// Round 12: rounds 7-11 established gateup is pinned at ~98us/30% MfmaUtil
// under every intra-kernel lever (3 schedules, dense tiling, XCD pinning,
// occupancy) -- all pipes 20-30% busy. Pivot to the other ~260us:
// (1) router_cast + transpose_cast fused into ONE prep_kernel (independent
//     work, block-range split; latency-bound router co-scheduled with
//     BW-bound transpose fills the machine).
// (2) combine_kernel deleted: down's epilogue does weighted atomicAdd f32
//     straight into out (2 adds/element, commutative; out memset up front).
//     Removes a launch + 64 MB of Hd round-trip traffic.

// ---------------- Kernel 1: prep = router (blocks 0..255) + weight
// transpose/cast (blocks 256..3327, 2 tiles per 512-thread block) ----------
__global__ __launch_bounds__(512) void prep_kernel(
    const float* __restrict__ x,      // [NTOK][D]
    const float* __restrict__ Wr,     // [D][E]
    int* __restrict__ cnt,            // [E*CNT_STRIDE] padded counters
    int* __restrict__ tok_of,         // [E][NTOK] (tok2 = t*2+slot)
    float* __restrict__ wt2,          // [2*NTOK] weight by tok2
    unsigned short* __restrict__ xb,  // [NTOK][D] bf16
    const float* __restrict__ Wg, const float* __restrict__ Wu,
    const float* __restrict__ Wd,
    unsigned short* __restrict__ WgT, unsigned short* __restrict__ WuT,
    unsigned short* __restrict__ WdT)
{
    const int tid = threadIdx.x;

    if (blockIdx.x >= 256) {
        // ---------- transpose/cast path: 2 64x64 tiles per block ----------
        __shared__ float tile[2][64][65];
        const int s = tid >> 8;           // sub-tile 0/1
        const int t2 = tid & 255;
        const int k = (blockIdx.x - 256) * 2 + s;   // 0..6143
        const int m = k >> 8;             // 0..23 (matrix)
        const int rem = k & 255;
        const int c0 = (rem & 15) * 64;   // src col tile (= dst row)
        const int r0 = (rem >> 4) * 64;   // src row tile (= dst col)
        const float* src;
        unsigned short* dst;
        if (m < 8)       { src = Wg + (size_t)m * 1048576;        dst = WgT + (size_t)m * 1048576; }
        else if (m < 16) { src = Wu + (size_t)(m - 8) * 1048576;  dst = WuT + (size_t)(m - 8) * 1048576; }
        else             { src = Wd + (size_t)(m - 16) * 1048576; dst = WdT + (size_t)(m - 16) * 1048576; }

        const int tr = t2 >> 4;           // 0..15
        const int tc = (t2 & 15) * 4;
        #pragma unroll
        for (int p = 0; p < 4; ++p) {
            float4 v = *(const float4*)(src + (size_t)(r0 + p * 16 + tr) * 1024 + c0 + tc);
            tile[s][p * 16 + tr][tc + 0] = v.x;
            tile[s][p * 16 + tr][tc + 1] = v.y;
            tile[s][p * 16 + tr][tc + 2] = v.z;
            tile[s][p * 16 + tr][tc + 3] = v.w;
        }
        __syncthreads();
        const int orow = t2 >> 3;         // 0..31
        const int ocol = (t2 & 7) * 8;
        #pragma unroll
        for (int p = 0; p < 2; ++p) {
            int fr = p * 32 + orow;       // dst row within tile (= src col)
            union { unsigned short us[8]; uint4 v; } pk;
            #pragma unroll
            for (int q = 0; q < 8; ++q) pk.us[q] = f2bf(tile[s][ocol + q][fr]);
            *(uint4*)&dst[(size_t)(c0 + fr) * 1024 + r0 + ocol] = pk.v;
        }
        return;
    }

    // ---------------- router path (blocks 0..255) -------------------------
    __shared__ int lcnt[E_DIM];
    __shared__ int lbase[E_DIM];
    __shared__ int lbuf[E_DIM][64];   // 32 tokens * 2 slots max per expert

    const int wv = tid >> 6;          // 0..7
    const int lane = tid & 63;
    if (tid < E_DIM) lcnt[tid] = 0;
    __syncthreads();

    #pragma unroll
    for (int it = 0; it < 4; ++it) {
        const int t = blockIdx.x * 32 + wv * 4 + it;
        const float* xrow = x + (size_t)t * D_DIM;
        unsigned short* xbrow = xb + (size_t)t * D_DIM;

        float p[E_DIM];
        #pragma unroll
        for (int e = 0; e < E_DIM; ++e) p[e] = 0.f;

        #pragma unroll
        for (int i = 0; i < 4; ++i) {
            const int d = i * 256 + lane * 4;
            float4 v = *(const float4*)(xrow + d);
            ushort4 o;
            o.x = f2bf(v.x); o.y = f2bf(v.y); o.z = f2bf(v.z); o.w = f2bf(v.w);
            *(ushort4*)(xbrow + d) = o;
            const float* wr = Wr + (size_t)d * E_DIM;
            float xv[4] = {v.x, v.y, v.z, v.w};
            #pragma unroll
            for (int q = 0; q < 4; ++q) {
                float4 w0 = *(const float4*)(wr + q * 8);
                float4 w1 = *(const float4*)(wr + q * 8 + 4);
                p[0] += xv[q] * w0.x; p[1] += xv[q] * w0.y;
                p[2] += xv[q] * w0.z; p[3] += xv[q] * w0.w;
                p[4] += xv[q] * w1.x; p[5] += xv[q] * w1.y;
                p[6] += xv[q] * w1.z; p[7] += xv[q] * w1.w;
            }
        }

        #pragma unroll
        for (int off = 32; off > 0; off >>= 1) {
            #pragma unroll
            for (int e = 0; e < E_DIM; ++e)
                p[e] += __shfl_xor(p[e], off, 64);
        }

        if (lane == 0) {
            float m = p[0];
            #pragma unroll
            for (int e = 1; e < E_DIM; ++e) m = fmaxf(m, p[e]);
            float pr[E_DIM], sum = 0.f;
            #pragma unroll
            for (int e = 0; e < E_DIM; ++e) { pr[e] = expf(p[e] - m); sum += pr[e]; }
            float inv = 1.f / sum;
            #pragma unroll
            for (int e = 0; e < E_DIM; ++e) pr[e] *= inv;
            // top-2 (strict > keeps lowest index on ties, matching lax.top_k)
            int e0 = 0;
            #pragma unroll
            for (int e = 1; e < E_DIM; ++e) if (pr[e] > pr[e0]) e0 = e;
            int e1 = (e0 == 0) ? 1 : 0;
            #pragma unroll
            for (int e = 0; e < E_DIM; ++e) { if (e != e0 && pr[e] > pr[e1]) e1 = e; }
            // second softmax over the two PROBABILITIES (faithful to reference)
            float b = expf(pr[e1] - pr[e0]);
            float w0 = 1.f / (1.f + b);
            float w1 = b / (1.f + b);
            int p0 = atomicAdd(&lcnt[e0], 1);
            lbuf[e0][p0] = t * 2 + 0;
            int p1 = atomicAdd(&lcnt[e1], 1);
            lbuf[e1][p1] = t * 2 + 1;
            wt2[t * 2 + 0] = w0;
            wt2[t * 2 + 1] = w1;
        }
    }
    __syncthreads();
    if (tid < E_DIM) lbase[tid] = atomicAdd(&cnt[tid * CNT_STRIDE], lcnt[tid]);
    __syncthreads();
    #pragma unroll
    for (int e = 0; e < E_DIM; ++e) {
        int n = lcnt[e];
        if (tid < n) tok_of[e * NTOK + lbase[e] + tid] = lbuf[e][tid];
    }
}

// ---------------- Kernel 4: fused gating+up MFMA GEMM + silu*mul ----------
// Dense-tiled: flat bid = wk*8 + colTile; block prefix-sums the padded
// counters to find (expert, rowBase). 128x128 tile, BK=32, 4 waves,
// double-buffered counted-vmcnt pipeline (round-1 schedule, best measured).
__global__ __launch_bounds__(256, 2) void gateup_mfma(
    const unsigned short* __restrict__ xb,    // [NTOK][D] bf16
    const unsigned short* __restrict__ WgT,   // [E][F][D] bf16 (B^T)
    const unsigned short* __restrict__ WuT,   // [E][F][D] bf16
    const int* __restrict__ cnt,
    const int* __restrict__ tok_of,
    unsigned short* __restrict__ H)           // [2*NTOK][F] bf16
{
    const int colTile = blockIdx.x & 7;       // bid%8 -> XCD: panel pinned per-XCD
    const int wk = blockIdx.x >> 3;           // global dense row tile
    int e = -1, rowBase = 0, rows = 0, tb = 0;
    #pragma unroll
    for (int q = 0; q < E_DIM; ++q) {
        int r = cnt[q * CNT_STRIDE];
        int nt = (r + 127) >> 7;
        if (e < 0 && wk < tb + nt) { e = q; rowBase = (wk - tb) << 7; rows = r; }
        tb += nt;
    }
    if (e < 0) return;                        // beyond total tiles (padding slack)
    const int n0 = colTile * 128;

    __shared__ short As[2][128 * 32];
    __shared__ short Bg[2][128 * 32];
    __shared__ short Bu[2][128 * 32];
    __shared__ int toks[128];

    const int tid = threadIdx.x;
    if (tid < 128) {
        int idx = rowBase + tid;
        toks[tid] = tok_of[e * NTOK + (idx < rows ? idx : rows - 1)];
    }
    __syncthreads();

    const int lane = tid & 63;
    const int w = tid >> 6;
    const int seg0 = w * 2, seg1 = w * 2 + 1;   // each wave stages 2 segs per buffer
    const int sr = lane >> 2;                   // 0..15 row within segment
    const int swz = (sr >> 1) & 3;
    const int sk = ((lane & 3) ^ swz) * 8;      // swizzled k-chunk (8 bf16 = 16B)

    const int ar0 = seg0 * 16 + sr;
    const int ar1 = seg1 * 16 + sr;
    const unsigned short* aG0 = xb + (size_t)(toks[ar0] >> 1) * D_DIM + sk;
    const unsigned short* aG1 = xb + (size_t)(toks[ar1] >> 1) * D_DIM + sk;
    const unsigned short* WgTe = WgT + (size_t)e * F_DIM * D_DIM;
    const unsigned short* WuTe = WuT + (size_t)e * F_DIM * D_DIM;
    const unsigned short* gG0 = WgTe + (size_t)(n0 + ar0) * D_DIM + sk;
    const unsigned short* gG1 = WgTe + (size_t)(n0 + ar1) * D_DIM + sk;
    const unsigned short* uG0 = WuTe + (size_t)(n0 + ar0) * D_DIM + sk;
    const unsigned short* uG1 = WuTe + (size_t)(n0 + ar1) * D_DIM + sk;

    const int mseg = (w >> 1) * 4;   // A segment base for this wave
    const int nseg = (w & 1) * 4;    // B segment base
    const int mbase = (w >> 1) * 64;
    const int nbase = (w & 1) * 64;
    const int fr = lane & 15;
    // reader offset within a segment (shorts): inverse of the staging swizzle
    const int rd = (4 * fr + ((lane >> 4) ^ ((fr >> 1) & 3))) * 8;

    f32x4 accg[4][4], accu[4][4];
    #pragma unroll
    for (int i = 0; i < 4; ++i)
        #pragma unroll
        for (int j = 0; j < 4; ++j) { accg[i][j] = (f32x4)(0.f); accu[i][j] = (f32x4)(0.f); }

    // 6 global_load_lds per thread per K-tile (kk in shorts: 32 shorts = 64 B)
    #define STAGE_GU(b, kk) do { \
        async_load16(aG0 + (kk), &As[b][seg0 * 512]); \
        async_load16(aG1 + (kk), &As[b][seg1 * 512]); \
        async_load16(gG0 + (kk), &Bg[b][seg0 * 512]); \
        async_load16(gG1 + (kk), &Bg[b][seg1 * 512]); \
        async_load16(uG0 + (kk), &Bu[b][seg0 * 512]); \
        async_load16(uG1 + (kk), &Bu[b][seg1 * 512]); \
    } while (0)

    const int NT = D_DIM / 32;       // 32 K-tiles
    STAGE_GU(0, 0);                  // 6 loads in flight
    STAGE_GU(1, 32);                 // 12 in flight

    #pragma unroll 2
    for (int t = 0; t < NT - 1; ++t) {
        const int b = t & 1;
        // buffer b's 6 loads are the oldest; next tile's 6 stay in flight
        asm volatile("s_waitcnt vmcnt(6)" ::: "memory");
        __builtin_amdgcn_s_barrier();

        bf16x8 a[4], g[4], u[4];
        #pragma unroll
        for (int i = 0; i < 4; ++i)
            a[i] = *(const bf16x8*)&As[b][(mseg + i) * 512 + rd];
        #pragma unroll
        for (int j = 0; j < 4; ++j) {
            g[j] = *(const bf16x8*)&Bg[b][(nseg + j) * 512 + rd];
            u[j] = *(const bf16x8*)&Bu[b][(nseg + j) * 512 + rd];
        }
        // all waves must finish reading buf b before anyone restages into it
        asm volatile("s_waitcnt lgkmcnt(0)" ::: "memory");
        __builtin_amdgcn_sched_barrier(0);
        __builtin_amdgcn_s_barrier();
        if (t < NT - 2) STAGE_GU(b, (t + 2) * 32);

        __builtin_amdgcn_s_setprio(1);
        #pragma unroll
        for (int i = 0; i < 4; ++i)
            #pragma unroll
            for (int j = 0; j < 4; ++j) {
                accg[i][j] = __builtin_amdgcn_mfma_f32_16x16x32_bf16(a[i], g[j], accg[i][j], 0, 0, 0);
                accu[i][j] = __builtin_amdgcn_mfma_f32_16x16x32_bf16(a[i], u[j], accu[i][j], 0, 0, 0);
            }
        __builtin_amdgcn_s_setprio(0);
    }
    {   // final tile (buffer 1): nothing left in flight afterwards
        asm volatile("s_waitcnt vmcnt(0)" ::: "memory");
        __builtin_amdgcn_s_barrier();
        bf16x8 a[4], g[4], u[4];
        #pragma unroll
        for (int i = 0; i < 4; ++i)
            a[i] = *(const bf16x8*)&As[1][(mseg + i) * 512 + rd];
        #pragma unroll
        for (int j = 0; j < 4; ++j) {
            g[j] = *(const bf16x8*)&Bg[1][(nseg + j) * 512 + rd];
            u[j] = *(const bf16x8*)&Bu[1][(nseg + j) * 512 + rd];
        }
        __builtin_amdgcn_s_setprio(1);
        #pragma unroll
        for (int i = 0; i < 4; ++i)
            #pragma unroll
            for (int j = 0; j < 4; ++j) {
                accg[i][j] = __builtin_amdgcn_mfma_f32_16x16x32_bf16(a[i], g[j], accg[i][j], 0, 0, 0);
                accu[i][j] = __builtin_amdgcn_mfma_f32_16x16x32_bf16(a[i], u[j], accu[i][j], 0, 0, 0);
            }
        __builtin_amdgcn_s_setprio(0);
    }
    #undef STAGE_GU

    // epilogue: C/D layout col=lane&15, row=(lane>>4)*4+reg
    const int erow = (lane >> 4) * 4;
    #pragma unroll
    for (int i = 0; i < 4; ++i) {
        #pragma unroll
        for (int r = 0; r < 4; ++r) {
            int row = mbase + i * 16 + erow + r;
            int idx = rowBase + row;
            if (idx < rows) {
                int tok2 = toks[row];
                unsigned short* hrow = H + (size_t)tok2 * F_DIM + n0 + nbase;
                #pragma unroll
                for (int j = 0; j < 4; ++j) {
                    float gg = accg[i][j][r];
                    float uu = accu[i][j][r];
                    float h = gg / (1.f + __expf(-gg)) * uu;
                    hrow[j * 16 + fr] = f2bf(h);
                }
            }
        }
    }
}

// ---------------- Kernel 5: down MFMA GEMM -> weighted atomic out ---------
// Dense-tiled like gateup; 128x128 tile, 4 waves, dbuf counted-vmcnt.
// Epilogue scales by wt2[tok2] and atomicAdds f32 into out (combine fused).
__global__ __launch_bounds__(256, 2) void down_mfma(
    const unsigned short* __restrict__ H,     // [2*NTOK][F] bf16
    const unsigned short* __restrict__ WdT,   // [E][D][F] bf16 (B^T)
    const int* __restrict__ cnt,
    const int* __restrict__ tok_of,
    const float* __restrict__ wt2,            // [2*NTOK]
    float* __restrict__ out)                  // [NTOK][D] f32 (pre-zeroed)
{
    const int colTile = blockIdx.x & 7;       // bid%8 -> XCD: panel pinned per-XCD
    const int wk = blockIdx.x >> 3;
    int e = -1, rowBase = 0, rows = 0, tb = 0;
    #pragma unroll
    for (int q = 0; q < E_DIM; ++q) {
        int r = cnt[q * CNT_STRIDE];
        int nt = (r + 127) >> 7;
        if (e < 0 && wk < tb + nt) { e = q; rowBase = (wk - tb) << 7; rows = r; }
        tb += nt;
    }
    if (e < 0) return;
    const int n0 = colTile * 128;

    __shared__ short As[2][128 * 32];
    __shared__ short Bs[2][128 * 32];
    __shared__ int toks[128];

    const int tid = threadIdx.x;
    if (tid < 128) {
        int idx = rowBase + tid;
        toks[tid] = tok_of[e * NTOK + (idx < rows ? idx : rows - 1)];
    }
    __syncthreads();

    const int lane = tid & 63;
    const int w = tid >> 6;
    const int seg0 = w * 2, seg1 = w * 2 + 1;
    const int sr = lane >> 2;
    const int swz = (sr >> 1) & 3;
    const int sk = ((lane & 3) ^ swz) * 8;

    const int ar0 = seg0 * 16 + sr;
    const int ar1 = seg1 * 16 + sr;
    const unsigned short* aG0 = H + (size_t)toks[ar0] * F_DIM + sk;
    const unsigned short* aG1 = H + (size_t)toks[ar1] * F_DIM + sk;
    const unsigned short* WdTe = WdT + (size_t)e * D_DIM * F_DIM;
    const unsigned short* bG0 = WdTe + (size_t)(n0 + ar0) * F_DIM + sk;
    const unsigned short* bG1 = WdTe + (size_t)(n0 + ar1) * F_DIM + sk;

    const int mseg = (w >> 1) * 4;
    const int nseg = (w & 1) * 4;
    const int mbase = (w >> 1) * 64;
    const int nbase = (w & 1) * 64;
    const int fr = lane & 15;
    const int rd = (4 * fr + ((lane >> 4) ^ ((fr >> 1) & 3))) * 8;

    f32x4 acc[4][4];
    #pragma unroll
    for (int i = 0; i < 4; ++i)
        #pragma unroll
        for (int j = 0; j < 4; ++j) acc[i][j] = (f32x4)(0.f);

    #define STAGE_D(b, kk) do { \
        async_load16(aG0 + (kk), &As[b][seg0 * 512]); \
        async_load16(aG1 + (kk), &As[b][seg1 * 512]); \
        async_load16(bG0 + (kk), &Bs[b][seg0 * 512]); \
        async_load16(bG1 + (kk), &Bs[b][seg1 * 512]); \
    } while (0)

    const int NT = F_DIM / 32;
    STAGE_D(0, 0);                   // 4 in flight
    STAGE_D(1, 32);                  // 8 in flight

    #pragma unroll 2
    for (int t = 0; t < NT - 1; ++t) {
        const int b = t & 1;
        asm volatile("s_waitcnt vmcnt(4)" ::: "memory");
        __builtin_amdgcn_s_barrier();

        bf16x8 a[4], bb[4];
        #pragma unroll
        for (int i = 0; i < 4; ++i)
            a[i] = *(const bf16x8*)&As[b][(mseg + i) * 512 + rd];
        #pragma unroll
        for (int j = 0; j < 4; ++j)
            bb[j] = *(const bf16x8*)&Bs[b][(nseg + j) * 512 + rd];

        asm volatile("s_waitcnt lgkmcnt(0)" ::: "memory");
        __builtin_amdgcn_sched_barrier(0);
        __builtin_amdgcn_s_barrier();
        if (t < NT - 2) STAGE_D(b, (t + 2) * 32);

        __builtin_amdgcn_s_setprio(1);
        #pragma unroll
        for (int i = 0; i < 4; ++i)
            #pragma unroll
            for (int j = 0; j < 4; ++j)
                acc[i][j] = __builtin_amdgcn_mfma_f32_16x16x32_bf16(a[i], bb[j], acc[i][j], 0, 0, 0);
        __builtin_amdgcn_s_setprio(0);
    }
    {   // final tile (buffer 1)
        asm volatile("s_waitcnt vmcnt(0)" ::: "memory");
        __builtin_amdgcn_s_barrier();
        bf16x8 a[4], bb[4];
        #pragma unroll
        for (int i = 0; i < 4; ++i)
            a[i] = *(const bf16x8*)&As[1][(mseg + i) * 512 + rd];
        #pragma unroll
        for (int j = 0; j < 4; ++j)
            bb[j] = *(const bf16x8*)&Bs[1][(nseg + j) * 512 + rd];
        __builtin_amdgcn_s_setprio(1);
        #pragma unroll
        for (int i = 0; i < 4; ++i)
            #pragma unroll
            for (int j = 0; j < 4; ++j)
                acc[i][j] = __builtin_amdgcn_mfma_f32_16x16x32_bf16(a[i], bb[j], acc[i][j], 0, 0, 0);
        __builtin_amdgcn_s_setprio(0);
    }
    #undef STAGE_D

    // epilogue: weighted atomic accumulate into out[token][d]
    const int erow = (lane >> 4) * 4;
    #pragma unroll
    for (int i = 0; i < 4; ++i) {
        #pragma unroll
        for (int r = 0; r < 4; ++r) {
            int row = mbase + i * 16 + erow + r;
            int idx = rowBase + row;
            if (idx < rows) {
                int tok2 = toks[row];
                float wgt = wt2[tok2];
                float* orow = out + (size_t)(tok2 >> 1) * D_DIM + n0 + nbase;
                #pragma unroll
                for (int j = 0; j < 4; ++j)
                    atomicAdd(&orow[j * 16 + fr], acc[i][j][r] * wgt);
            }
        }
    }
}

extern "C" void kernel_launch(void* const* d_in, const int* in_sizes, int n_in,
                              void* d_out, int out_size, void* d_ws, size_t ws_size,
                              hipStream_t stream) {
    const float* x  = (const float*)d_in[0];   // [B,T,D]
    const float* Wr = (const float*)d_in[1];   // [D,E]
    const float* Wg = (const float*)d_in[2];   // [E,D,F]
    const float* Wu = (const float*)d_in[3];   // [E,D,F]
    const float* Wd = (const float*)d_in[4];   // [E,F,D]
    float* out = (float*)d_out;

    char* ws = (char*)d_ws;
    int*   cnt    = (int*)ws;                                // 1 KB (padded counters)
    int*   tok_of = (int*)(ws + 1024);                       // 256 KB
    float* wt2    = (float*)(ws + 1024 + E_DIM * NTOK * 4);  // 64 KB
    char*  base   = ws + (1 << 20);
    unsigned short* xb  = (unsigned short*)(base);                    // 16 MB
    unsigned short* WgT = (unsigned short*)(base + (16ll << 20));     // 16 MB
    unsigned short* WuT = (unsigned short*)(base + (32ll << 20));     // 16 MB
    unsigned short* WdT = (unsigned short*)(base + (48ll << 20));     // 16 MB
    unsigned short* H   = (unsigned short*)(base + (64ll << 20));     // 32 MB

    hipMemsetAsync(cnt, 0, E_DIM * CNT_STRIDE * sizeof(int), stream);
    hipMemsetAsync(out, 0, (size_t)NTOK * D_DIM * sizeof(float), stream);

    // 256 router blocks + 3072 transpose blocks (2 tiles each)
    prep_kernel<<<256 + 3072, 512, 0, stream>>>(
        x, Wr, cnt, tok_of, wt2, xb, Wg, Wu, Wd, WgT, WuT, WdT);

    // dense grid: total row tiles <= 2*NTOK/128 + E (per-expert ceil padding)
    const int MAX_TILES = (2 * NTOK) / 128 + E_DIM;   // 136
    gateup_mfma<<<dim3(MAX_TILES * 8), 256, 0, stream>>>(
        xb, WgT, WuT, cnt, tok_of, H);
    down_mfma<<<dim3(MAX_TILES * 8), 256, 0, stream>>>(
        H, WdT, cnt, tok_of, wt2, out);
}

// Round 7
// 343.651 us; speedup vs baseline: 1.0960x; 1.0960x over previous
//
#include <hip/hip_runtime.h>
#include <hip/hip_bf16.h>
#include <math.h>

// B=4, T=2048, D=1024, E=8, F=1024, top_k=2
#define NTOK 8192   // B*T
#define D_DIM 1024
#define E_DIM 8
#define F_DIM 1024

// cnt is padded: counter for expert e lives at cnt[e*32] (128 B apart) so the
// 8 experts' global atomics land in different L2 lines.
#define CNT_STRIDE 32

typedef __attribute__((ext_vector_type(8))) short bf16x8;
typedef __attribute__((ext_vector_type(4))) float f32x4;

typedef const __attribute__((address_space(1))) unsigned int* as1_uint_ptr;
typedef __attribute__((address_space(3))) unsigned int* as3_uint_ptr;

__device__ __forceinline__ void async_load16(const void* g, void* l) {
    // per-lane global address; LDS dest = wave-uniform base + lane*16
    __builtin_amdgcn_global_load_lds((as1_uint_ptr)g, (as3_uint_ptr)l, 16, 0, 0);
}

__device__ __forceinline__ float bf2f(unsigned short b) {
    unsigned int u = ((unsigned int)b) << 16;
    return __builtin_bit_cast(float, u);
}
__device__ __forceinline__ unsigned short f2bf(float f) {
    __hip_bfloat16 h = __float2bfloat16(f);
    return __builtin_bit_cast(unsigned short, h);
}

// LDS swizzle: stage lane s loads k-chunk (s&3)^((row>>1)&3); readers invert.
// SQ_LDS_BANK_CONFLICT measured 0.
//
// Round 13: round-12's atomicAdd-out fusion regressed down_mfma 75->106us
// (65MB of contended f32 L2 RMWs, MfmaUtil 12.8%) -> reverted to Hd+combine.
// prep fusion (router+transpose one kernel) kept. New: expert-SORTED H
// layout -- gateup writes H row (rowPrefix[e]+idx) instead of scattering by
// tok2; down's A staging then reads contiguous rows (no toks indirection in
// the load address path, sequential L2 access). Both kernels derive
// rowPrefix from the same deterministic cnt prefix-scan.

// ---------------- Kernel 1: prep = router (blocks 0..255) + weight
// transpose/cast (blocks 256..3327, 2 tiles per 512-thread block) ----------
__global__ __launch_bounds__(512) void prep_kernel(
    const float* __restrict__ x,      // [NTOK][D]
    const float* __restrict__ Wr,     // [D][E]
    int* __restrict__ cnt,            // [E*CNT_STRIDE] padded counters
    int* __restrict__ tok_of,         // [E][NTOK] (tok2 = t*2+slot)
    float* __restrict__ wt2,          // [2*NTOK] weight by tok2
    unsigned short* __restrict__ xb,  // [NTOK][D] bf16
    const float* __restrict__ Wg, const float* __restrict__ Wu,
    const float* __restrict__ Wd,
    unsigned short* __restrict__ WgT, unsigned short* __restrict__ WuT,
    unsigned short* __restrict__ WdT)
{
    const int tid = threadIdx.x;

    if (blockIdx.x >= 256) {
        // ---------- transpose/cast path: 2 64x64 tiles per block ----------
        __shared__ float tile[2][64][65];
        const int s = tid >> 8;           // sub-tile 0/1
        const int t2 = tid & 255;
        const int k = (blockIdx.x - 256) * 2 + s;   // 0..6143
        const int m = k >> 8;             // 0..23 (matrix)
        const int rem = k & 255;
        const int c0 = (rem & 15) * 64;   // src col tile (= dst row)
        const int r0 = (rem >> 4) * 64;   // src row tile (= dst col)
        const float* src;
        unsigned short* dst;
        if (m < 8)       { src = Wg + (size_t)m * 1048576;        dst = WgT + (size_t)m * 1048576; }
        else if (m < 16) { src = Wu + (size_t)(m - 8) * 1048576;  dst = WuT + (size_t)(m - 8) * 1048576; }
        else             { src = Wd + (size_t)(m - 16) * 1048576; dst = WdT + (size_t)(m - 16) * 1048576; }

        const int tr = t2 >> 4;           // 0..15
        const int tc = (t2 & 15) * 4;
        #pragma unroll
        for (int p = 0; p < 4; ++p) {
            float4 v = *(const float4*)(src + (size_t)(r0 + p * 16 + tr) * 1024 + c0 + tc);
            tile[s][p * 16 + tr][tc + 0] = v.x;
            tile[s][p * 16 + tr][tc + 1] = v.y;
            tile[s][p * 16 + tr][tc + 2] = v.z;
            tile[s][p * 16 + tr][tc + 3] = v.w;
        }
        __syncthreads();
        const int orow = t2 >> 3;         // 0..31
        const int ocol = (t2 & 7) * 8;
        #pragma unroll
        for (int p = 0; p < 2; ++p) {
            int fr = p * 32 + orow;       // dst row within tile (= src col)
            union { unsigned short us[8]; uint4 v; } pk;
            #pragma unroll
            for (int q = 0; q < 8; ++q) pk.us[q] = f2bf(tile[s][ocol + q][fr]);
            *(uint4*)&dst[(size_t)(c0 + fr) * 1024 + r0 + ocol] = pk.v;
        }
        return;
    }

    // ---------------- router path (blocks 0..255) -------------------------
    __shared__ int lcnt[E_DIM];
    __shared__ int lbase[E_DIM];
    __shared__ int lbuf[E_DIM][64];   // 32 tokens * 2 slots max per expert

    const int wv = tid >> 6;          // 0..7
    const int lane = tid & 63;
    if (tid < E_DIM) lcnt[tid] = 0;
    __syncthreads();

    #pragma unroll
    for (int it = 0; it < 4; ++it) {
        const int t = blockIdx.x * 32 + wv * 4 + it;
        const float* xrow = x + (size_t)t * D_DIM;
        unsigned short* xbrow = xb + (size_t)t * D_DIM;

        float p[E_DIM];
        #pragma unroll
        for (int e = 0; e < E_DIM; ++e) p[e] = 0.f;

        #pragma unroll
        for (int i = 0; i < 4; ++i) {
            const int d = i * 256 + lane * 4;
            float4 v = *(const float4*)(xrow + d);
            ushort4 o;
            o.x = f2bf(v.x); o.y = f2bf(v.y); o.z = f2bf(v.z); o.w = f2bf(v.w);
            *(ushort4*)(xbrow + d) = o;
            const float* wr = Wr + (size_t)d * E_DIM;
            float xv[4] = {v.x, v.y, v.z, v.w};
            #pragma unroll
            for (int q = 0; q < 4; ++q) {
                float4 w0 = *(const float4*)(wr + q * 8);
                float4 w1 = *(const float4*)(wr + q * 8 + 4);
                p[0] += xv[q] * w0.x; p[1] += xv[q] * w0.y;
                p[2] += xv[q] * w0.z; p[3] += xv[q] * w0.w;
                p[4] += xv[q] * w1.x; p[5] += xv[q] * w1.y;
                p[6] += xv[q] * w1.z; p[7] += xv[q] * w1.w;
            }
        }

        #pragma unroll
        for (int off = 32; off > 0; off >>= 1) {
            #pragma unroll
            for (int e = 0; e < E_DIM; ++e)
                p[e] += __shfl_xor(p[e], off, 64);
        }

        if (lane == 0) {
            float m = p[0];
            #pragma unroll
            for (int e = 1; e < E_DIM; ++e) m = fmaxf(m, p[e]);
            float pr[E_DIM], sum = 0.f;
            #pragma unroll
            for (int e = 0; e < E_DIM; ++e) { pr[e] = expf(p[e] - m); sum += pr[e]; }
            float inv = 1.f / sum;
            #pragma unroll
            for (int e = 0; e < E_DIM; ++e) pr[e] *= inv;
            // top-2 (strict > keeps lowest index on ties, matching lax.top_k)
            int e0 = 0;
            #pragma unroll
            for (int e = 1; e < E_DIM; ++e) if (pr[e] > pr[e0]) e0 = e;
            int e1 = (e0 == 0) ? 1 : 0;
            #pragma unroll
            for (int e = 0; e < E_DIM; ++e) { if (e != e0 && pr[e] > pr[e1]) e1 = e; }
            // second softmax over the two PROBABILITIES (faithful to reference)
            float b = expf(pr[e1] - pr[e0]);
            float w0 = 1.f / (1.f + b);
            float w1 = b / (1.f + b);
            int p0 = atomicAdd(&lcnt[e0], 1);
            lbuf[e0][p0] = t * 2 + 0;
            int p1 = atomicAdd(&lcnt[e1], 1);
            lbuf[e1][p1] = t * 2 + 1;
            wt2[t * 2 + 0] = w0;
            wt2[t * 2 + 1] = w1;
        }
    }
    __syncthreads();
    if (tid < E_DIM) lbase[tid] = atomicAdd(&cnt[tid * CNT_STRIDE], lcnt[tid]);
    __syncthreads();
    #pragma unroll
    for (int e = 0; e < E_DIM; ++e) {
        int n = lcnt[e];
        if (tid < n) tok_of[e * NTOK + lbase[e] + tid] = lbuf[e][tid];
    }
}

// ---------------- Kernel 4: fused gating+up MFMA GEMM + silu*mul ----------
// Dense-tiled: flat bid = wk*8 + colTile; block prefix-sums the padded
// counters to find (expert, rowBase, rowPrefix). 128x128 tile, BK=32,
// 4 waves, double-buffered counted-vmcnt pipeline. H written SORTED:
// row = rowPrefix + idx (contiguous per expert).
__global__ __launch_bounds__(256, 2) void gateup_mfma(
    const unsigned short* __restrict__ xb,    // [NTOK][D] bf16
    const unsigned short* __restrict__ WgT,   // [E][F][D] bf16 (B^T)
    const unsigned short* __restrict__ WuT,   // [E][F][D] bf16
    const int* __restrict__ cnt,
    const int* __restrict__ tok_of,
    unsigned short* __restrict__ H)           // [2*NTOK][F] bf16, e-sorted
{
    const int colTile = blockIdx.x & 7;       // bid%8 -> XCD: panel pinned per-XCD
    const int wk = blockIdx.x >> 3;           // global dense row tile
    int e = -1, rowBase = 0, rows = 0, tb = 0, rp = 0;
    #pragma unroll
    for (int q = 0; q < E_DIM; ++q) {
        int r = cnt[q * CNT_STRIDE];
        int nt = (r + 127) >> 7;
        if (e < 0) {
            if (wk < tb + nt) { e = q; rowBase = (wk - tb) << 7; rows = r; }
            else rp += r;
        }
        tb += nt;
    }
    if (e < 0) return;                        // beyond total tiles (padding slack)
    const int n0 = colTile * 128;

    __shared__ short As[2][128 * 32];
    __shared__ short Bg[2][128 * 32];
    __shared__ short Bu[2][128 * 32];
    __shared__ int toks[128];

    const int tid = threadIdx.x;
    if (tid < 128) {
        int idx = rowBase + tid;
        toks[tid] = tok_of[e * NTOK + (idx < rows ? idx : rows - 1)];
    }
    __syncthreads();

    const int lane = tid & 63;
    const int w = tid >> 6;
    const int seg0 = w * 2, seg1 = w * 2 + 1;   // each wave stages 2 segs per buffer
    const int sr = lane >> 2;                   // 0..15 row within segment
    const int swz = (sr >> 1) & 3;
    const int sk = ((lane & 3) ^ swz) * 8;      // swizzled k-chunk (8 bf16 = 16B)

    const int ar0 = seg0 * 16 + sr;
    const int ar1 = seg1 * 16 + sr;
    const unsigned short* aG0 = xb + (size_t)(toks[ar0] >> 1) * D_DIM + sk;
    const unsigned short* aG1 = xb + (size_t)(toks[ar1] >> 1) * D_DIM + sk;
    const unsigned short* WgTe = WgT + (size_t)e * F_DIM * D_DIM;
    const unsigned short* WuTe = WuT + (size_t)e * F_DIM * D_DIM;
    const unsigned short* gG0 = WgTe + (size_t)(n0 + ar0) * D_DIM + sk;
    const unsigned short* gG1 = WgTe + (size_t)(n0 + ar1) * D_DIM + sk;
    const unsigned short* uG0 = WuTe + (size_t)(n0 + ar0) * D_DIM + sk;
    const unsigned short* uG1 = WuTe + (size_t)(n0 + ar1) * D_DIM + sk;

    const int mseg = (w >> 1) * 4;   // A segment base for this wave
    const int nseg = (w & 1) * 4;    // B segment base
    const int mbase = (w >> 1) * 64;
    const int nbase = (w & 1) * 64;
    const int fr = lane & 15;
    // reader offset within a segment (shorts): inverse of the staging swizzle
    const int rd = (4 * fr + ((lane >> 4) ^ ((fr >> 1) & 3))) * 8;

    f32x4 accg[4][4], accu[4][4];
    #pragma unroll
    for (int i = 0; i < 4; ++i)
        #pragma unroll
        for (int j = 0; j < 4; ++j) { accg[i][j] = (f32x4)(0.f); accu[i][j] = (f32x4)(0.f); }

    // 6 global_load_lds per thread per K-tile (kk in shorts: 32 shorts = 64 B)
    #define STAGE_GU(b, kk) do { \
        async_load16(aG0 + (kk), &As[b][seg0 * 512]); \
        async_load16(aG1 + (kk), &As[b][seg1 * 512]); \
        async_load16(gG0 + (kk), &Bg[b][seg0 * 512]); \
        async_load16(gG1 + (kk), &Bg[b][seg1 * 512]); \
        async_load16(uG0 + (kk), &Bu[b][seg0 * 512]); \
        async_load16(uG1 + (kk), &Bu[b][seg1 * 512]); \
    } while (0)

    const int NT = D_DIM / 32;       // 32 K-tiles
    STAGE_GU(0, 0);                  // 6 loads in flight
    STAGE_GU(1, 32);                 // 12 in flight

    #pragma unroll 2
    for (int t = 0; t < NT - 1; ++t) {
        const int b = t & 1;
        // buffer b's 6 loads are the oldest; next tile's 6 stay in flight
        asm volatile("s_waitcnt vmcnt(6)" ::: "memory");
        __builtin_amdgcn_s_barrier();

        bf16x8 a[4], g[4], u[4];
        #pragma unroll
        for (int i = 0; i < 4; ++i)
            a[i] = *(const bf16x8*)&As[b][(mseg + i) * 512 + rd];
        #pragma unroll
        for (int j = 0; j < 4; ++j) {
            g[j] = *(const bf16x8*)&Bg[b][(nseg + j) * 512 + rd];
            u[j] = *(const bf16x8*)&Bu[b][(nseg + j) * 512 + rd];
        }
        // all waves must finish reading buf b before anyone restages into it
        asm volatile("s_waitcnt lgkmcnt(0)" ::: "memory");
        __builtin_amdgcn_sched_barrier(0);
        __builtin_amdgcn_s_barrier();
        if (t < NT - 2) STAGE_GU(b, (t + 2) * 32);

        __builtin_amdgcn_s_setprio(1);
        #pragma unroll
        for (int i = 0; i < 4; ++i)
            #pragma unroll
            for (int j = 0; j < 4; ++j) {
                accg[i][j] = __builtin_amdgcn_mfma_f32_16x16x32_bf16(a[i], g[j], accg[i][j], 0, 0, 0);
                accu[i][j] = __builtin_amdgcn_mfma_f32_16x16x32_bf16(a[i], u[j], accu[i][j], 0, 0, 0);
            }
        __builtin_amdgcn_s_setprio(0);
    }
    {   // final tile (buffer 1): nothing left in flight afterwards
        asm volatile("s_waitcnt vmcnt(0)" ::: "memory");
        __builtin_amdgcn_s_barrier();
        bf16x8 a[4], g[4], u[4];
        #pragma unroll
        for (int i = 0; i < 4; ++i)
            a[i] = *(const bf16x8*)&As[1][(mseg + i) * 512 + rd];
        #pragma unroll
        for (int j = 0; j < 4; ++j) {
            g[j] = *(const bf16x8*)&Bg[1][(nseg + j) * 512 + rd];
            u[j] = *(const bf16x8*)&Bu[1][(nseg + j) * 512 + rd];
        }
        __builtin_amdgcn_s_setprio(1);
        #pragma unroll
        for (int i = 0; i < 4; ++i)
            #pragma unroll
            for (int j = 0; j < 4; ++j) {
                accg[i][j] = __builtin_amdgcn_mfma_f32_16x16x32_bf16(a[i], g[j], accg[i][j], 0, 0, 0);
                accu[i][j] = __builtin_amdgcn_mfma_f32_16x16x32_bf16(a[i], u[j], accu[i][j], 0, 0, 0);
            }
        __builtin_amdgcn_s_setprio(0);
    }
    #undef STAGE_GU

    // epilogue: C/D layout col=lane&15, row=(lane>>4)*4+reg; sorted H write
    const int erow = (lane >> 4) * 4;
    #pragma unroll
    for (int i = 0; i < 4; ++i) {
        #pragma unroll
        for (int r = 0; r < 4; ++r) {
            int row = mbase + i * 16 + erow + r;
            int idx = rowBase + row;
            if (idx < rows) {
                unsigned short* hrow = H + (size_t)(rp + idx) * F_DIM + n0 + nbase;
                #pragma unroll
                for (int j = 0; j < 4; ++j) {
                    float gg = accg[i][j][r];
                    float uu = accu[i][j][r];
                    float h = gg / (1.f + __expf(-gg)) * uu;
                    hrow[j * 16 + fr] = f2bf(h);
                }
            }
        }
    }
}

// ---------------- Kernel 5: down MFMA GEMM -> Hd (unweighted) -------------
// Dense-tiled; A rows read CONTIGUOUSLY from sorted H (no gather in the
// staging path). 128x128 tile, 4 waves, dbuf counted-vmcnt.
__global__ __launch_bounds__(256, 2) void down_mfma(
    const unsigned short* __restrict__ H,     // [2*NTOK][F] bf16, e-sorted
    const unsigned short* __restrict__ WdT,   // [E][D][F] bf16 (B^T)
    const int* __restrict__ cnt,
    const int* __restrict__ tok_of,
    unsigned short* __restrict__ Hd)          // [2*NTOK][D] bf16, by tok2
{
    const int colTile = blockIdx.x & 7;       // bid%8 -> XCD: panel pinned per-XCD
    const int wk = blockIdx.x >> 3;
    int e = -1, rowBase = 0, rows = 0, tb = 0, rp = 0;
    #pragma unroll
    for (int q = 0; q < E_DIM; ++q) {
        int r = cnt[q * CNT_STRIDE];
        int nt = (r + 127) >> 7;
        if (e < 0) {
            if (wk < tb + nt) { e = q; rowBase = (wk - tb) << 7; rows = r; }
            else rp += r;
        }
        tb += nt;
    }
    if (e < 0) return;
    const int n0 = colTile * 128;

    __shared__ short As[2][128 * 32];
    __shared__ short Bs[2][128 * 32];
    __shared__ int toks[128];

    const int tid = threadIdx.x;
    if (tid < 128) {
        int idx = rowBase + tid;
        toks[tid] = tok_of[e * NTOK + (idx < rows ? idx : rows - 1)];
    }
    __syncthreads();

    const int lane = tid & 63;
    const int w = tid >> 6;
    const int seg0 = w * 2, seg1 = w * 2 + 1;
    const int sr = lane >> 2;
    const int swz = (sr >> 1) & 3;
    const int sk = ((lane & 3) ^ swz) * 8;

    const int ar0 = seg0 * 16 + sr;
    const int ar1 = seg1 * 16 + sr;
    // contiguous sorted-H rows (clamped to expert range)
    int ra0 = rowBase + ar0; if (ra0 >= rows) ra0 = rows - 1;
    int ra1 = rowBase + ar1; if (ra1 >= rows) ra1 = rows - 1;
    const unsigned short* aG0 = H + (size_t)(rp + ra0) * F_DIM + sk;
    const unsigned short* aG1 = H + (size_t)(rp + ra1) * F_DIM + sk;
    const unsigned short* WdTe = WdT + (size_t)e * D_DIM * F_DIM;
    const unsigned short* bG0 = WdTe + (size_t)(n0 + ar0) * F_DIM + sk;
    const unsigned short* bG1 = WdTe + (size_t)(n0 + ar1) * F_DIM + sk;

    const int mseg = (w >> 1) * 4;
    const int nseg = (w & 1) * 4;
    const int mbase = (w >> 1) * 64;
    const int nbase = (w & 1) * 64;
    const int fr = lane & 15;
    const int rd = (4 * fr + ((lane >> 4) ^ ((fr >> 1) & 3))) * 8;

    f32x4 acc[4][4];
    #pragma unroll
    for (int i = 0; i < 4; ++i)
        #pragma unroll
        for (int j = 0; j < 4; ++j) acc[i][j] = (f32x4)(0.f);

    #define STAGE_D(b, kk) do { \
        async_load16(aG0 + (kk), &As[b][seg0 * 512]); \
        async_load16(aG1 + (kk), &As[b][seg1 * 512]); \
        async_load16(bG0 + (kk), &Bs[b][seg0 * 512]); \
        async_load16(bG1 + (kk), &Bs[b][seg1 * 512]); \
    } while (0)

    const int NT = F_DIM / 32;
    STAGE_D(0, 0);                   // 4 in flight
    STAGE_D(1, 32);                  // 8 in flight

    #pragma unroll 2
    for (int t = 0; t < NT - 1; ++t) {
        const int b = t & 1;
        asm volatile("s_waitcnt vmcnt(4)" ::: "memory");
        __builtin_amdgcn_s_barrier();

        bf16x8 a[4], bb[4];
        #pragma unroll
        for (int i = 0; i < 4; ++i)
            a[i] = *(const bf16x8*)&As[b][(mseg + i) * 512 + rd];
        #pragma unroll
        for (int j = 0; j < 4; ++j)
            bb[j] = *(const bf16x8*)&Bs[b][(nseg + j) * 512 + rd];

        asm volatile("s_waitcnt lgkmcnt(0)" ::: "memory");
        __builtin_amdgcn_sched_barrier(0);
        __builtin_amdgcn_s_barrier();
        if (t < NT - 2) STAGE_D(b, (t + 2) * 32);

        __builtin_amdgcn_s_setprio(1);
        #pragma unroll
        for (int i = 0; i < 4; ++i)
            #pragma unroll
            for (int j = 0; j < 4; ++j)
                acc[i][j] = __builtin_amdgcn_mfma_f32_16x16x32_bf16(a[i], bb[j], acc[i][j], 0, 0, 0);
        __builtin_amdgcn_s_setprio(0);
    }
    {   // final tile (buffer 1)
        asm volatile("s_waitcnt vmcnt(0)" ::: "memory");
        __builtin_amdgcn_s_barrier();
        bf16x8 a[4], bb[4];
        #pragma unroll
        for (int i = 0; i < 4; ++i)
            a[i] = *(const bf16x8*)&As[1][(mseg + i) * 512 + rd];
        #pragma unroll
        for (int j = 0; j < 4; ++j)
            bb[j] = *(const bf16x8*)&Bs[1][(nseg + j) * 512 + rd];
        __builtin_amdgcn_s_setprio(1);
        #pragma unroll
        for (int i = 0; i < 4; ++i)
            #pragma unroll
            for (int j = 0; j < 4; ++j)
                acc[i][j] = __builtin_amdgcn_mfma_f32_16x16x32_bf16(a[i], bb[j], acc[i][j], 0, 0, 0);
        __builtin_amdgcn_s_setprio(0);
    }
    #undef STAGE_D

    const int erow = (lane >> 4) * 4;
    #pragma unroll
    for (int i = 0; i < 4; ++i) {
        #pragma unroll
        for (int r = 0; r < 4; ++r) {
            int row = mbase + i * 16 + erow + r;
            int idx = rowBase + row;
            if (idx < rows) {
                int tok2 = toks[row];
                unsigned short* orow = Hd + (size_t)tok2 * D_DIM + n0 + nbase;
                #pragma unroll
                for (int j = 0; j < 4; ++j)
                    orow[j * 16 + fr] = f2bf(acc[i][j][r]);
            }
        }
    }
}

// ---------------- Kernel 6: combine out[t] = w0*Hd[2t] + w1*Hd[2t+1] ------
__global__ __launch_bounds__(256) void combine_kernel(
    const unsigned short* __restrict__ Hd,
    const float* __restrict__ wt2,
    float* __restrict__ out)
{
    const int t = blockIdx.x;
    const int tid = threadIdx.x;
    const float w0 = wt2[2 * t];
    const float w1 = wt2[2 * t + 1];
    const int c = tid * 4;
    ushort4 a = *(const ushort4*)&Hd[(size_t)(2 * t) * D_DIM + c];
    ushort4 b = *(const ushort4*)&Hd[(size_t)(2 * t + 1) * D_DIM + c];
    float4 o;
    o.x = w0 * bf2f(a.x) + w1 * bf2f(b.x);
    o.y = w0 * bf2f(a.y) + w1 * bf2f(b.y);
    o.z = w0 * bf2f(a.z) + w1 * bf2f(b.z);
    o.w = w0 * bf2f(a.w) + w1 * bf2f(b.w);
    *(float4*)(out + (size_t)t * D_DIM + c) = o;
}

extern "C" void kernel_launch(void* const* d_in, const int* in_sizes, int n_in,
                              void* d_out, int out_size, void* d_ws, size_t ws_size,
                              hipStream_t stream) {
    const float* x  = (const float*)d_in[0];   // [B,T,D]
    const float* Wr = (const float*)d_in[1];   // [D,E]
    const float* Wg = (const float*)d_in[2];   // [E,D,F]
    const float* Wu = (const float*)d_in[3];   // [E,D,F]
    const float* Wd = (const float*)d_in[4];   // [E,F,D]
    float* out = (float*)d_out;

    char* ws = (char*)d_ws;
    int*   cnt    = (int*)ws;                                // 1 KB (padded counters)
    int*   tok_of = (int*)(ws + 1024);                       // 256 KB
    float* wt2    = (float*)(ws + 1024 + E_DIM * NTOK * 4);  // 64 KB
    char*  base   = ws + (1 << 20);
    unsigned short* xb  = (unsigned short*)(base);                    // 16 MB
    unsigned short* Hd  = (unsigned short*)(base);                    // 32 MB, aliases xb+WgT (dead by then)
    unsigned short* WgT = (unsigned short*)(base + (16ll << 20));     // 16 MB
    unsigned short* WuT = (unsigned short*)(base + (32ll << 20));     // 16 MB
    unsigned short* WdT = (unsigned short*)(base + (48ll << 20));     // 16 MB
    unsigned short* H   = (unsigned short*)(base + (64ll << 20));     // 32 MB

    hipMemsetAsync(cnt, 0, E_DIM * CNT_STRIDE * sizeof(int), stream);

    // 256 router blocks + 3072 transpose blocks (2 tiles each)
    prep_kernel<<<256 + 3072, 512, 0, stream>>>(
        x, Wr, cnt, tok_of, wt2, xb, Wg, Wu, Wd, WgT, WuT, WdT);

    // dense grid: total row tiles <= 2*NTOK/128 + E (per-expert ceil padding)
    const int MAX_TILES = (2 * NTOK) / 128 + E_DIM;   // 136
    gateup_mfma<<<dim3(MAX_TILES * 8), 256, 0, stream>>>(
        xb, WgT, WuT, cnt, tok_of, H);
    down_mfma<<<dim3(MAX_TILES * 8), 256, 0, stream>>>(
        H, WdT, cnt, tok_of, Hd);
    combine_kernel<<<NTOK, 256, 0, stream>>>(Hd, wt2, out);
}